// Round 2
// baseline (145.157 us; speedup 1.0000x reference)
//
#include <hip/hip_runtime.h>

// PrototypicalNetwork: out[q,c] = -1/8 * sum_b sqrt(max(q2[q] + p2[b,c] - 2*qp[b,q,c], 0))
// bf16 MFMA (16x16x32) for qp GEMM (M=65536, N=1024, K=128).
// R2: software-pipelined b-loop — register double-buffer at half-b (2 c-tile)
// granularity so b-frag L2 loads stay in flight across MFMA + sqrt epilogue
// (AITER-style fine-grained vmcnt, no barriers in the hot loop).

#define DIM   128
#define NCLS  128
#define SHOTS 32
#define NB    8
#define NQ    65536

using short8 = __attribute__((ext_vector_type(8))) short;
using f32x4  = __attribute__((ext_vector_type(4))) float;

__device__ __forceinline__ unsigned short f2bf(float x) {
  union { float f; unsigned u; } v; v.f = x;
  unsigned r = v.u + 0x7fffu + ((v.u >> 16) & 1u);   // round-to-nearest-even
  return (unsigned short)(r >> 16);
}

__device__ __forceinline__ float fast_sqrt(float x) {
#if __has_builtin(__builtin_amdgcn_sqrtf)
  return __builtin_amdgcn_sqrtf(x);   // raw v_sqrt_f32, no fixup sequence
#else
  return sqrtf(x);
#endif
}

// ---------------------------------------------------------------------------
// Kernel 1: protos (bootstrap-mean) -> bf16 in MFMA B-fragment-major layout,
// plus p2[b,c] = ||proto||^2 (fp32). Fragment layout for 16x16x32 bf16 B:
// lane holds B[n=lane&15][k=(lane>>4)*8+j]. Slot = (b*8+ct)*4+kiter; one slot
// = 64 lanes * 16 B = 1 KB contiguous (one wave global_load_dwordx4).
// ---------------------------------------------------------------------------
__global__ __launch_bounds__(128) void proto_kernel(
    const float* __restrict__ sup, const int* __restrict__ bidx,
    unsigned short* __restrict__ pfrag, float* __restrict__ p2) {
  int bc = blockIdx.x;            // b*128 + c
  int c  = bc & (NCLS - 1);
  int d  = threadIdx.x;           // 0..127 = feature dim
  __shared__ int   sidx[SHOTS];
  __shared__ float wsum[2];
  if (d < SHOTS) sidx[d] = bidx[bc * SHOTS + d];
  __syncthreads();
  float acc = 0.f;
  const float* base = sup + c * SHOTS * DIM + d;
  #pragma unroll
  for (int s = 0; s < SHOTS; ++s) acc += base[sidx[s] * DIM];
  float proto = acc * (1.0f / 32.0f);

  int b     = bc >> 7;
  int ct    = c >> 4, l15c = c & 15;
  int kiter = d >> 5, quad = (d >> 3) & 3, j = d & 7;
  int lane  = l15c + (quad << 4);
  int slot  = (b * 8 + ct) * 4 + kiter;
  pfrag[slot * 512 + lane * 8 + j] = f2bf(proto);

  float sq = proto * proto;       // p2 from fp32 protos (matches reference)
  #pragma unroll
  for (int off = 32; off > 0; off >>= 1) sq += __shfl_down(sq, off, 64);
  if ((d & 63) == 0) wsum[d >> 6] = sq;
  __syncthreads();
  if (d == 0) p2[bc] = wsum[0] + wsum[1];
}

// ---------------------------------------------------------------------------
// Kernel 2: per block: 64 query rows x 128 classes; 4 waves.
// wave = (ctg<<1)|mtg; wave owns m-tiles {2mtg,2mtg+1}, c-tiles {4ctg..4ctg+3}.
// b-loop pipelined: bufX covers ct2 {0,1} (h=0), bufY covers ct2 {2,3} (h=1);
// while group g computes, group g+1's 8 dwordx4 loads are in flight.
// ---------------------------------------------------------------------------
__global__ __launch_bounds__(256) void dist_kernel(
    const float* __restrict__ q, const uint4* __restrict__ pfrag,
    const float* __restrict__ p2, float* __restrict__ out) {
  int tid  = threadIdx.x;
  int wave = tid >> 6, lane = tid & 63;
  int l15  = lane & 15, quad = lane >> 4;
  int mtg  = wave & 1, ctg = wave >> 1;
  int q0   = blockIdx.x << 6;

  __shared__ float q2p[64][4];     // per-row, per-quad partial |q|^2

  // --- load A-fragments (Q) directly from global in fragment layout ---
  // A-layout: lane holds A[m=lane&15][k=quad*8+j] -> 8 consecutive floats.
  short8 af[2][4];
  #pragma unroll
  for (int mt2 = 0; mt2 < 2; ++mt2) {
    int rrow = (mtg * 2 + mt2) * 16 + l15;
    const float* qr = q + (size_t)(q0 + rrow) * DIM + quad * 8;
    float s = 0.f;
    #pragma unroll
    for (int k = 0; k < 4; ++k) {
      float4 x0 = *reinterpret_cast<const float4*>(qr + k * 32);
      float4 x1 = *reinterpret_cast<const float4*>(qr + k * 32 + 4);
      s += x0.x*x0.x + x0.y*x0.y + x0.z*x0.z + x0.w*x0.w
         + x1.x*x1.x + x1.y*x1.y + x1.z*x1.z + x1.w*x1.w;
      short8 a;
      a[0] = (short)f2bf(x0.x); a[1] = (short)f2bf(x0.y);
      a[2] = (short)f2bf(x0.z); a[3] = (short)f2bf(x0.w);
      a[4] = (short)f2bf(x1.x); a[5] = (short)f2bf(x1.y);
      a[6] = (short)f2bf(x1.z); a[7] = (short)f2bf(x1.w);
      af[mt2][k] = a;
    }
    if (ctg == 0) q2p[rrow][quad] = s;   // each row written by exactly one lane
  }
  __syncthreads();

  // q2 per accumulator row: C/D layout row = quad*4 + r (within m-tile)
  f32x4 q2r[2];
  #pragma unroll
  for (int mt2 = 0; mt2 < 2; ++mt2) {
    int r0 = (mtg * 2 + mt2) * 16 + quad * 4;
    f32x4 v;
    #pragma unroll
    for (int r = 0; r < 4; ++r) {
      float4 pp = *reinterpret_cast<const float4*>(&q2p[r0 + r][0]);
      v[r] = pp.x + pp.y + pp.z + pp.w;
    }
    q2r[mt2] = v;
  }

  f32x4 oacc[2][4];
  #pragma unroll
  for (int i = 0; i < 2; ++i)
    #pragma unroll
    for (int jj = 0; jj < 4; ++jj)
      oacc[i][jj] = (f32x4){0.f, 0.f, 0.f, 0.f};

  // ---- pipelined b-loop ----
  // group(b, h): c-tiles ct = ctg*4 + h*2 + {0,1}; 8 frags (2 ct x 4 k) + 2 p2.
  uint4 bufX[8], bufY[8];
  float p2X[2], p2Y[2];

  #define LOAD_GROUP(BUF, P2V, B, H)                                          \
    {                                                                         \
      _Pragma("unroll")                                                       \
      for (int jj = 0; jj < 2; ++jj) {                                        \
        int ct = ctg * 4 + (H) * 2 + jj;                                      \
        const uint4* bp = pfrag + (size_t)(((B) * 8 + ct) * 4) * 64 + lane;   \
        _Pragma("unroll")                                                     \
        for (int k = 0; k < 4; ++k) BUF[jj * 4 + k] = bp[k * 64];             \
        P2V[jj] = p2[(B) * NCLS + ct * 16 + l15];                             \
      }                                                                       \
    }

  #define COMPUTE_GROUP(BUF, P2V, H)                                          \
    {                                                                         \
      _Pragma("unroll")                                                       \
      for (int jj = 0; jj < 2; ++jj) {                                        \
        int c2 = (H) * 2 + jj;                                                \
        f32x4 qp0 = (f32x4){0.f, 0.f, 0.f, 0.f};                              \
        f32x4 qp1 = (f32x4){0.f, 0.f, 0.f, 0.f};                              \
        _Pragma("unroll")                                                     \
        for (int k = 0; k < 4; ++k) {                                         \
          short8 bfk = __builtin_bit_cast(short8, BUF[jj * 4 + k]);           \
          qp0 = __builtin_amdgcn_mfma_f32_16x16x32_bf16(af[0][k], bfk, qp0, 0, 0, 0); \
          qp1 = __builtin_amdgcn_mfma_f32_16x16x32_bf16(af[1][k], bfk, qp1, 0, 0, 0); \
        }                                                                     \
        _Pragma("unroll")                                                     \
        for (int r = 0; r < 4; ++r) {                                         \
          float t0 = q2r[0][r] + P2V[jj];                                     \
          float t1 = q2r[1][r] + P2V[jj];                                     \
          float d0 = fmaf(-2.0f, qp0[r], t0);                                 \
          float d1 = fmaf(-2.0f, qp1[r], t1);                                 \
          oacc[0][c2][r] += fast_sqrt(fmaxf(d0, 0.0f));                       \
          oacc[1][c2][r] += fast_sqrt(fmaxf(d1, 0.0f));                       \
        }                                                                     \
      }                                                                       \
    }

  LOAD_GROUP(bufX, p2X, 0, 0)
  #pragma unroll 1
  for (int i = 0; i < NB; ++i) {
    int bn = (i + 1) & (NB - 1);           // clamp wraps last prefetch to b=0
    LOAD_GROUP(bufY, p2Y, i, 1)            // in flight across X's compute
    COMPUTE_GROUP(bufX, p2X, 0)
    LOAD_GROUP(bufX, p2X, bn, 0)           // in flight across Y's compute
    COMPUTE_GROUP(bufY, p2Y, 1)
  }
  #undef LOAD_GROUP
  #undef COMPUTE_GROUP

  // store: row = q0 + mt*16 + quad*4 + r, col = ct*16 + l15 (nontemporal:
  // 32 MB streamed output, keep it out of L2 so pfrag/query stay hot)
  #pragma unroll
  for (int mt2 = 0; mt2 < 2; ++mt2)
    #pragma unroll
    for (int ct2 = 0; ct2 < 4; ++ct2) {
      int col = (ctg * 4 + ct2) * 16 + l15;
      #pragma unroll
      for (int r = 0; r < 4; ++r) {
        int row = q0 + (mtg * 2 + mt2) * 16 + quad * 4 + r;
        __builtin_nontemporal_store(-0.125f * oacc[mt2][ct2][r],
                                    &out[(size_t)row * NCLS + col]);
      }
    }
}

extern "C" void kernel_launch(void* const* d_in, const int* in_sizes, int n_in,
                              void* d_out, int out_size, void* d_ws, size_t ws_size,
                              hipStream_t stream) {
  const float* sup   = (const float*)d_in[0];   // [4096,128] f32
  // d_in[1] = support_labels (unused: sorted/balanced by construction)
  const float* query = (const float*)d_in[2];   // [65536,128] f32
  const int*   bidx  = (const int*)d_in[3];     // [8,128,32] i32
  float* out = (float*)d_out;                   // [65536,128] f32

  unsigned short* pfrag = (unsigned short*)d_ws;              // 8*128*128 bf16 = 256 KB
  float* p2 = (float*)((char*)d_ws + (size_t)NB * NCLS * DIM * 2); // 4 KB

  proto_kernel<<<NB * NCLS, 128, 0, stream>>>(sup, bidx, pfrag, p2);
  dist_kernel<<<NQ / 64, 256, 0, stream>>>(query, (const uint4*)pfrag, p2, out);
}